// Round 1
// baseline (214.468 us; speedup 1.0000x reference)
//
#include <hip/hip_runtime.h>

// QuantumRegressionModel: 16-qubit statevector, 3 layers x (16 rotations + CNOT chain),
// PauliZ features + linear head. Batch 64, DIM 65536, fp32.
//
// v2: occupancy-rebalanced split (16 amps/thread everywhere -> 4 waves/SIMD, was 2).
//  * kP: wires 6..15 (bits 9..0). Per-wave 1024-amp subcube, no LDS, no barriers.
//        Register gates: wires 6,7 (bits 9,8) and 14,15 (bits 1,0); shuffle gates 8..13 (bits 7..2).
//  * kQ: wires 0..5. Wires 0..3 on per-thread strided bits 15..12; wires 4,5 on thread-id
//        bits t7,t6 (index bits 11,10) via a single radix-4 LDS exchange (fused U4 (x) U5).
//  * CNOT chain == Gray gather psi_new[j] = psi_old[j ^ (j>>1)] -> folded into the NEXT
//    kP's load addressing (bit-width independent: float4-window + component swizzle).
//  * Features on pre-perm state: sign_q(m) = (-1)^{parity(m >> (15-q))}; factorizes over
//    (k bits 15..12, thread bits 11..0) -> fused into final kQ (kQF). Final state never stored.
//
// Wire q <-> global index bit (15-q). State = separate re/im fp32 planes.

struct G8 { float r00,i00,r01,i01,r10,i10,r11,i11; };

__device__ __forceinline__ G8 loadG(const float* __restrict__ p) {
  G8 g;
  g.r00=p[0]; g.i00=p[1]; g.r01=p[2]; g.i01=p[3];
  g.r10=p[4]; g.i10=p[5]; g.r11=p[6]; g.i11=p[7];
  return g;
}

// complex 2x2: (x0,x1) <- U * (x0,x1), scalars by reference
__device__ __forceinline__ void cmul2(const G8& g, float& r0, float& i0, float& r1, float& i1) {
  const float nr0 = g.r00*r0 - g.i00*i0 + g.r01*r1 - g.i01*i1;
  const float ni0 = g.r00*i0 + g.i00*r0 + g.r01*i1 + g.i01*r1;
  const float nr1 = g.r10*r0 - g.i10*i0 + g.r11*r1 - g.i11*i1;
  const float ni1 = g.r10*i0 + g.i10*r0 + g.r11*i1 + g.i11*r1;
  r0=nr0; i0=ni0; r1=nr1; i1=ni1;
}

// Build 48 fused unitaries U = Rz(tz)Ry(ty)Rx(tx); zero feats accumulator.
__global__ void kPrep(const float* __restrict__ vp, float* __restrict__ U,
                      float* __restrict__ feats) {
  const int i = threadIdx.x;
  if (i < 48) {
    const float tx = vp[i*6+0], ty = vp[i*6+1], tz = vp[i*6+2];
    float sx, cx, sy, cy, sz, cz;
    sincosf(0.5f*tx, &sx, &cx);
    sincosf(0.5f*ty, &sy, &cy);
    sincosf(0.5f*tz, &sz, &cz);
    const float m00r = cy*cx,  m00i = sy*sx;
    const float m01r = -sy*cx, m01i = -cy*sx;
    const float m10r = sy*cx,  m10i = -cy*sx;
    const float m11r = cy*cx,  m11i = -sy*sx;
    float* o = U + i*8;
    o[0] = cz*m00r + sz*m00i;  o[1] = cz*m00i - sz*m00r;
    o[2] = cz*m01r + sz*m01i;  o[3] = cz*m01i - sz*m01r;
    o[4] = cz*m10r - sz*m10i;  o[5] = cz*m10i + sz*m10r;
    o[6] = cz*m11r - sz*m11i;  o[7] = cz*m11i + sz*m11r;
  }
  for (int j = i; j < 1024; j += 64) feats[j] = 0.f;
}

// kP: wires 6..15 (bits 9..0). One wave = 1024-amp subcube, 16 amps/thread.
// Layout: per-thread bits {9,8}=k, {1,0}=e (float4 I/O); lane bits {7..2}; W = bits 15..10.
// GATHER=1: fold previous layer's CNOT-chain perm into the load: read src[g(j)], g(j)=j^(j>>1).
template<int GATHER>
__global__ void __launch_bounds__(256, 4) kP(const float* __restrict__ sr, const float* __restrict__ si,
                                             float* __restrict__ dr, float* __restrict__ di,
                                             const float* __restrict__ Ul) {
  const int t = threadIdx.x;
  const int lane = t & 63;
  const int wv = t >> 6;
  const int b = blockIdx.x >> 4;
  const int W = ((blockIdx.x & 15) << 2) | wv;         // bits 15..10
  const size_t bb = (size_t)b << 16;
  const int ebase = (W << 10) | (lane << 2);           // j with k=e=0
  float xr[16], xi[16];                                 // a = k*4 + e

  if (GATHER) {
    // g(j) permutes within the aligned float4: component = gray2(e) ^ (j2<<1), j2 = lane&1.
    const bool sw = (lane & 1);
    #pragma unroll
    for (int k = 0; k < 4; ++k) {
      const int base = ebase | (k << 8);
      const int a4 = (base ^ (base >> 1)) & ~3;
      const float4 vr = *(const float4*)(sr + bb + a4);
      const float4 vi = *(const float4*)(si + bb + a4);
      // gray2 = {0,1,3,2}; sw XORs component index with 2
      xr[k*4+0] = sw ? vr.z : vr.x;  xi[k*4+0] = sw ? vi.z : vi.x;
      xr[k*4+1] = sw ? vr.w : vr.y;  xi[k*4+1] = sw ? vi.w : vi.y;
      xr[k*4+2] = sw ? vr.y : vr.w;  xi[k*4+2] = sw ? vi.y : vi.w;
      xr[k*4+3] = sw ? vr.x : vr.z;  xi[k*4+3] = sw ? vi.x : vi.z;
    }
  } else {
    #pragma unroll
    for (int k = 0; k < 4; ++k) {
      const int base = ebase | (k << 8);
      const float4 vr = *(const float4*)(sr + bb + base);
      const float4 vi = *(const float4*)(si + bb + base);
      xr[k*4+0]=vr.x; xr[k*4+1]=vr.y; xr[k*4+2]=vr.z; xr[k*4+3]=vr.w;
      xi[k*4+0]=vi.x; xi[k*4+1]=vi.y; xi[k*4+2]=vi.z; xi[k*4+3]=vi.w;
    }
  }

  // Register gates on k bits: kb=1 -> bit9 -> wire6; kb=0 -> bit8 -> wire7.
  #pragma unroll
  for (int g = 0; g < 2; ++g) {
    const int kb = 1 - g;
    const G8 U = loadG(Ul + (6 + g)*8);
    #pragma unroll
    for (int p = 0; p < 2; ++p) {
      const int k0 = ((p >> kb) << (kb + 1)) | (p & ((1 << kb) - 1));
      const int k1 = k0 | (1 << kb);
      #pragma unroll
      for (int e = 0; e < 4; ++e)
        cmul2(U, xr[k0*4+e], xi[k0*4+e], xr[k1*4+e], xi[k1*4+e]);
    }
  }

  // Shuffle gates on lane bits 5..0 -> bits 7..2 -> wires 8..13.
  #pragma unroll
  for (int g = 0; g < 6; ++g) {
    const int lb = 5 - g;
    const int mask = 1 << lb;
    const G8 U = loadG(Ul + (8 + g)*8);
    const bool hi = (lane >> lb) & 1;
    const float ar = hi ? U.r11 : U.r00, ai = hi ? U.i11 : U.i00;
    const float br = hi ? U.r10 : U.r01, bi = hi ? U.i10 : U.i01;
    #pragma unroll
    for (int a = 0; a < 16; ++a) {
      const float pr = __shfl_xor(xr[a], mask);
      const float pi_ = __shfl_xor(xi[a], mask);
      const float nr = ar*xr[a] - ai*xi[a] + br*pr - bi*pi_;
      const float ni = ar*xi[a] + ai*xr[a] + br*pi_ + bi*pr;
      xr[a] = nr; xi[a] = ni;
    }
  }

  // Register gates on e bits: bit1 -> wire14, bit0 -> wire15.
  {
    const G8 U = loadG(Ul + 14*8);
    #pragma unroll
    for (int k = 0; k < 4; ++k) {
      cmul2(U, xr[k*4+0], xi[k*4+0], xr[k*4+2], xi[k*4+2]);
      cmul2(U, xr[k*4+1], xi[k*4+1], xr[k*4+3], xi[k*4+3]);
    }
  }
  {
    const G8 U = loadG(Ul + 15*8);
    #pragma unroll
    for (int k = 0; k < 4; ++k) {
      cmul2(U, xr[k*4+0], xi[k*4+0], xr[k*4+1], xi[k*4+1]);
      cmul2(U, xr[k*4+2], xi[k*4+2], xr[k*4+3], xi[k*4+3]);
    }
  }

  #pragma unroll
  for (int k = 0; k < 4; ++k) {
    const int base = ebase | (k << 8);
    float4 vr, vi;
    vr.x=xr[k*4+0]; vr.y=xr[k*4+1]; vr.z=xr[k*4+2]; vr.w=xr[k*4+3];
    vi.x=xi[k*4+0]; vi.y=xi[k*4+1]; vi.z=xi[k*4+2]; vi.w=xi[k*4+3];
    *(float4*)(dr + bb + base) = vr;
    *(float4*)(di + bb + base) = vi;
  }
}

// Shared body for kQ/kQF: load 16 strided amps, wires 0..3 (k bits 15..12) in regs,
// wires 4,5 (bits 11,10 = t7,t6) via one radix-4 LDS exchange with fused M = U4 (x) U5.
// LDS layout: 8 chunks of 1024 floats: chunk kc = re k-group, chunk 4+kc = im k-group,
// each [t][4] -> contiguous b128 per lane on both write and partner-read (conflict-free).
__device__ __forceinline__ void qBody(const float* __restrict__ r, const float* __restrict__ im,
                                      const float* __restrict__ Ul, float* lds,
                                      size_t base, int t, float (&xr)[16], float (&xi)[16]) {
  #pragma unroll
  for (int k = 0; k < 16; ++k) {
    xr[k] = r[base + ((size_t)k << 12)];
    xi[k] = im[base + ((size_t)k << 12)];
  }
  // wires 0..3 on k-bits 3..0 (bits 15..12)
  #pragma unroll
  for (int g = 0; g < 4; ++g) {
    const int kb = 3 - g;
    const G8 U = loadG(Ul + g*8);
    #pragma unroll
    for (int p = 0; p < 8; ++p) {
      const int i0 = ((p >> kb) << (kb + 1)) | (p & ((1 << kb) - 1));
      const int i1 = i0 | (1 << kb);
      cmul2(U, xr[i0], xi[i0], xr[i1], xi[i1]);
    }
  }
  // stage to LDS
  #pragma unroll
  for (int kc = 0; kc < 4; ++kc) {
    *(float4*)&lds[kc*1024 + t*4]     = make_float4(xr[kc*4+0], xr[kc*4+1], xr[kc*4+2], xr[kc*4+3]);
    *(float4*)&lds[(4+kc)*1024 + t*4] = make_float4(xi[kc*4+0], xi[kc*4+1], xi[kc*4+2], xi[kc*4+3]);
  }
  __syncthreads();
  // own quadrant p = (t7,t6); partner-relative coefficients (compile-time indexed):
  // Mj0 = diag*diag (own), Mj1 = diag*off (flip t6), Mj2 = off*diag (flip t7), Mj3 = off*off.
  const int p1 = (t >> 7) & 1, p0 = (t >> 6) & 1;
  const G8 U4 = loadG(Ul + 4*8), U5 = loadG(Ul + 5*8);
  const float Adr = p1 ? U4.r11 : U4.r00, Adi = p1 ? U4.i11 : U4.i00;
  const float Aor = p1 ? U4.r10 : U4.r01, Aoi = p1 ? U4.i10 : U4.i01;
  const float Bdr = p0 ? U5.r11 : U5.r00, Bdi = p0 ? U5.i11 : U5.i00;
  const float Bor = p0 ? U5.r10 : U5.r01, Boi = p0 ? U5.i10 : U5.i01;
  const float M0r = Adr*Bdr - Adi*Bdi, M0i = Adr*Bdi + Adi*Bdr;
  const float M1r = Adr*Bor - Adi*Boi, M1i = Adr*Boi + Adi*Bor;
  const float M2r = Aor*Bdr - Aoi*Bdi, M2i = Aor*Bdi + Aoi*Bdr;
  const float M3r = Aor*Bor - Aoi*Boi, M3i = Aor*Boi + Aoi*Bor;
  const int t1 = (t ^ 64) * 4, t2 = (t ^ 128) * 4, t3 = (t ^ 192) * 4;
  #pragma unroll
  for (int kc = 0; kc < 4; ++kc) {
    const float4 v1r = *(const float4*)&lds[kc*1024 + t1];
    const float4 v1i = *(const float4*)&lds[(4+kc)*1024 + t1];
    const float4 v2r = *(const float4*)&lds[kc*1024 + t2];
    const float4 v2i = *(const float4*)&lds[(4+kc)*1024 + t2];
    const float4 v3r = *(const float4*)&lds[kc*1024 + t3];
    const float4 v3i = *(const float4*)&lds[(4+kc)*1024 + t3];
    const float p1r[4] = {v1r.x, v1r.y, v1r.z, v1r.w}, p1i[4] = {v1i.x, v1i.y, v1i.z, v1i.w};
    const float p2r[4] = {v2r.x, v2r.y, v2r.z, v2r.w}, p2i[4] = {v2i.x, v2i.y, v2i.z, v2i.w};
    const float p3r[4] = {v3r.x, v3r.y, v3r.z, v3r.w}, p3i[4] = {v3i.x, v3i.y, v3i.z, v3i.w};
    #pragma unroll
    for (int e = 0; e < 4; ++e) {
      const int a = kc*4 + e;
      const float nr = M0r*xr[a] - M0i*xi[a] + M1r*p1r[e] - M1i*p1i[e]
                     + M2r*p2r[e] - M2i*p2i[e] + M3r*p3r[e] - M3i*p3i[e];
      const float ni = M0r*xi[a] + M0i*xr[a] + M1r*p1i[e] + M1i*p1r[e]
                     + M2r*p2i[e] + M2i*p2r[e] + M3r*p3i[e] + M3i*p3r[e];
      xr[a] = nr; xi[a] = ni;
    }
  }
}

// kQ: wires 0..5, in-place. Block = batch x c (bits 9..6); thread covers bits {15..12,11,10,5..0}.
__global__ void __launch_bounds__(256, 4) kQ(float* __restrict__ r, float* __restrict__ im,
                                             const float* __restrict__ Ul) {
  __shared__ float lds[8192];
  const int t = threadIdx.x;
  const int b = blockIdx.x >> 4, c = blockIdx.x & 15;
  const size_t base = ((size_t)b << 16) | ((t >> 6) << 10) | (c << 6) | (t & 63);
  float xr[16], xi[16];
  qBody(r, im, Ul, lds, base, t, xr, xi);
  #pragma unroll
  for (int k = 0; k < 16; ++k) {
    r[base + ((size_t)k << 12)]  = xr[k];
    im[base + ((size_t)k << 12)] = xi[k];
  }
}

// kQF: final-layer kQ + fused PauliZ features (final CNOT perm folded via gray-decode signs).
// f_q = sum_m |amp(m)|^2 * (-1)^{parity(m >> (15-q))}.
__global__ void __launch_bounds__(256, 4) kQF(const float* __restrict__ r, const float* __restrict__ im,
                                              const float* __restrict__ Ul, float* __restrict__ feats) {
  __shared__ float lds[8192];
  const int t = threadIdx.x;
  const int b = blockIdx.x >> 4, c = blockIdx.x & 15;
  const size_t base = ((size_t)b << 16) | ((t >> 6) << 10) | (c << 6) | (t & 63);
  float xr[16], xi[16];
  qBody(r, im, Ul, lds, base, t, xr, xi);
  // Signs for wires 0..3 depend only on k = m[15:12]; wires 4..15 = per-thread sign x S3.
  float S0=0.f, S1=0.f, S2=0.f, S3=0.f;
  #pragma unroll
  for (int k = 0; k < 16; ++k) {
    const float p = xr[k]*xr[k] + xi[k]*xi[k];
    const int k3=(k>>3)&1, k2=(k>>2)&1, k1=(k>>1)&1, k0=k&1;
    S0 += k3 ? -p : p;
    S1 += (k3^k2) ? -p : p;
    S2 += (k3^k2^k1) ? -p : p;
    S3 += (k3^k2^k1^k0) ? -p : p;
  }
  // 12-bit thread-local index bits m[11:0]; v_b = parity(m11..m_b) (prefix-from-top).
  int u = ((t >> 6) << 10) | (c << 6) | (t & 63);
  int v = u; v ^= v >> 1; v ^= v >> 2; v ^= v >> 4; v ^= v >> 8;
  float f[16];
  f[0]=S0; f[1]=S1; f[2]=S2; f[3]=S3;
  #pragma unroll
  for (int q = 4; q < 16; ++q)
    f[q] = ((v >> (15 - q)) & 1) ? -S3 : S3;
  #pragma unroll
  for (int q = 0; q < 16; ++q) {
    float s = f[q];
    s += __shfl_xor(s, 32); s += __shfl_xor(s, 16); s += __shfl_xor(s, 8);
    s += __shfl_xor(s, 4);  s += __shfl_xor(s, 2);  s += __shfl_xor(s, 1);
    f[q] = s;
  }
  __syncthreads();                       // done reading gate data; reuse lds for reduction
  const int w = t >> 6;
  if ((t & 63) == 0) {
    #pragma unroll
    for (int q = 0; q < 16; ++q) lds[w*16 + q] = f[q];
  }
  __syncthreads();
  if (t < 16) {
    const float s = lds[t] + lds[16 + t] + lds[32 + t] + lds[48 + t];
    atomicAdd(&feats[b*16 + t], s);
  }
}

__global__ void kHead(const float* __restrict__ feats, const float* __restrict__ w,
                      const float* __restrict__ bias, float* __restrict__ out) {
  const int b = threadIdx.x;
  if (b < 64) {
    float v = bias[0];
    #pragma unroll
    for (int q = 0; q < 16; ++q) v += feats[b*16 + q] * w[q];
    out[b] = v;
  }
}

extern "C" void kernel_launch(void* const* d_in, const int* in_sizes, int n_in,
                              void* d_out, int out_size, void* d_ws, size_t ws_size,
                              hipStream_t stream) {
  float* in_r = (float*)d_in[0];            // (64, 65536) fp32 — clobbered; harness restores
  float* in_i = (float*)d_in[1];
  const float* vp = (const float*)d_in[2];  // (3,16,6)
  const float* hw = (const float*)d_in[3];  // (1,16)
  const float* hb = (const float*)d_in[4];  // (1,)
  float* out = (float*)d_out;               // (64,) fp32

  float* ws_r  = (float*)d_ws;              // 4,194,304 floats
  float* ws_i  = ws_r + 4194304ull;
  float* Ubuf  = ws_i + 4194304ull;         // 48*8 floats
  float* feats = Ubuf + 384;                // 64*16 floats

  kPrep<<<1, 64, 0, stream>>>(vp, Ubuf, feats);
  // layer 0
  kP<0><<<1024, 256, 0, stream>>>(in_r, in_i, ws_r, ws_i, Ubuf + 0*128);
  kQ   <<<1024, 256, 0, stream>>>(ws_r, ws_i, Ubuf + 0*128);
  // layer 1 (perm of layer 0 folded into gather-load)
  kP<1><<<1024, 256, 0, stream>>>(ws_r, ws_i, in_r, in_i, Ubuf + 1*128);
  kQ   <<<1024, 256, 0, stream>>>(in_r, in_i, Ubuf + 1*128);
  // layer 2
  kP<1><<<1024, 256, 0, stream>>>(in_r, in_i, ws_r, ws_i, Ubuf + 2*128);
  kQF  <<<1024, 256, 0, stream>>>(ws_r, ws_i, Ubuf + 2*128, feats);
  kHead<<<1, 64, 0, stream>>>(feats, hw, hb, out);
}